// Round 3
// baseline (418.137 us; speedup 1.0000x reference)
//
#include <hip/hip_runtime.h>
#include <hip/hip_bf16.h>

typedef __bf16 bf16;
typedef __bf16 bf16x4 __attribute__((ext_vector_type(4)));
typedef __bf16 bf16x8 __attribute__((ext_vector_type(8)));
typedef float floatx4 __attribute__((ext_vector_type(4)));

#define EMBED 1024
#define VOCAB 32000
#define BB    4
#define SS    4096
#define NTOK  (BB * SS)   // 16384
#define NKV   2048        // K and V concatenated
#define NSEG  16          // out_gemm d-segments
#define TCH   32          // attention t-chunk per block
#define NCH   (SS / TCH)  // 128 chunks per batch

// ---- async global->LDS, 16B per lane (lane-contiguous LDS dest required) ----
__device__ __forceinline__ void async_copy16(void* lds, const void* g) {
    __builtin_amdgcn_global_load_lds(
        (const __attribute__((address_space(1))) unsigned int*)g,
        (__attribute__((address_space(3))) unsigned int*)lds, 16, 0, 0);
}

// ============================================================================
// K1 "prep": blockIdx < 4096  -> gather h = embed[x] (4 tokens/block), stash
//            last token per batch into h_last (fp32).
//            blockIdx >= 4096 -> transpose+convert qkv_w[:,1024:3072] -> WkvT.
// ============================================================================
__global__ void prep(const int* __restrict__ x,
                     const float* __restrict__ embed,
                     const float* __restrict__ qkv_w,
                     bf16* __restrict__ h,
                     float* __restrict__ h_last,
                     bf16* __restrict__ WkvT) {
    __shared__ float T[32 * 33];
    int bid = blockIdx.x, tid = threadIdx.x;
    if (bid < NTOK / 4) {
        int t0 = bid * 4;
        int r0 = x[t0], r1 = x[t0 + 1], r2 = x[t0 + 2], r3 = x[t0 + 3];
        float4 v0 = *(const float4*)(embed + (size_t)r0 * EMBED + tid * 4);
        float4 v1 = *(const float4*)(embed + (size_t)r1 * EMBED + tid * 4);
        float4 v2 = *(const float4*)(embed + (size_t)r2 * EMBED + tid * 4);
        float4 v3 = *(const float4*)(embed + (size_t)r3 * EMBED + tid * 4);
        bf16x4 o0, o1, o2, o3;
        o0.x=(bf16)v0.x; o0.y=(bf16)v0.y; o0.z=(bf16)v0.z; o0.w=(bf16)v0.w;
        o1.x=(bf16)v1.x; o1.y=(bf16)v1.y; o1.z=(bf16)v1.z; o1.w=(bf16)v1.w;
        o2.x=(bf16)v2.x; o2.y=(bf16)v2.y; o2.z=(bf16)v2.z; o2.w=(bf16)v2.w;
        o3.x=(bf16)v3.x; o3.y=(bf16)v3.y; o3.z=(bf16)v3.z; o3.w=(bf16)v3.w;
        *(bf16x4*)(h + (size_t)(t0 + 0) * EMBED + tid * 4) = o0;
        *(bf16x4*)(h + (size_t)(t0 + 1) * EMBED + tid * 4) = o1;
        *(bf16x4*)(h + (size_t)(t0 + 2) * EMBED + tid * 4) = o2;
        *(bf16x4*)(h + (size_t)(t0 + 3) * EMBED + tid * 4) = o3;
        if ((bid & 1023) == 1023) {           // t0+3 is token 4095 of batch
            int b = bid >> 10;
            *(float4*)(h_last + b * EMBED + tid * 4) = v3;
        }
    } else {
        int bw = bid - NTOK / 4;              // 0..2047
        int n0 = (bw & 63) * 32, d0 = (bw >> 6) * 32;
        int c = tid & 31, r = tid >> 5;
#pragma unroll
        for (int i = 0; i < 4; ++i) {
            int d = r + i * 8;
            T[c * 33 + d] = qkv_w[(size_t)(d0 + d) * (3 * EMBED) + EMBED + n0 + c];
        }
        __syncthreads();
#pragma unroll
        for (int i = 0; i < 4; ++i) {
            int n = r + i * 8;
            WkvT[(size_t)(n0 + n) * EMBED + d0 + c] = (bf16)T[n * 33 + c];
        }
    }
}

// ============================================================================
// K2: q[b] = h_last[b] @ qkv_w[:, 0:1024] + qkv_b[0:1024]
// grid 32 blocks x 256 threads: block covers 32 j-cols; wave w = batch w;
// lanes 0-31/32-63 split d in halves, shuffle-combined.
// ============================================================================
__global__ void q_fused(const float* __restrict__ h_last,
                        const float* __restrict__ qkv_w,
                        const float* __restrict__ qkv_b,
                        float* __restrict__ q) {
    __shared__ float hs[BB * EMBED];          // 16 KiB
    int tid = threadIdx.x;
    for (int i = tid; i < BB * EMBED / 4; i += 256)
        *(float4*)(hs + i * 4) = *(const float4*)(h_last + i * 4);
    __syncthreads();
    int w = tid >> 6, lane = tid & 63;
    int j = blockIdx.x * 32 + (lane & 31);
    int dh = lane >> 5;                       // 0 or 1: d-half
    const float* hb = hs + w * EMBED + dh * 512;
    float acc = 0.0f;
#pragma unroll 8
    for (int d = 0; d < 512; ++d)
        acc += hb[d] * qkv_w[(size_t)(dh * 512 + d) * (3 * EMBED) + j];
    acc += __shfl_down(acc, 32);
    if (lane < 32) q[w * EMBED + j] = acc + qkv_b[j];
}

// ============================================================================
// K3: the big GEMM (byte-identical to round 1/2). KV = h @ WkvT^T + bias.
// ============================================================================
__global__ __launch_bounds__(256, 2) void gemm_kv(
    const bf16* __restrict__ A,    // 16384 x 1024 row-major
    const bf16* __restrict__ BT,   // 2048 x 1024
    const float* __restrict__ bias,// 2048
    bf16* __restrict__ C) {        // 16384 x 2048
    __shared__ bf16 As[128 * 32];
    __shared__ bf16 Bs[128 * 32];
    const int K = EMBED;
    int tid = threadIdx.x;
    int wave = tid >> 6, lane = tid & 63;
    int wm = wave >> 1, wn = wave & 1;
    int quad = lane >> 4, l16 = lane & 15;

    floatx4 acc[4][4];
#pragma unroll
    for (int a = 0; a < 4; ++a)
#pragma unroll
        for (int b = 0; b < 4; ++b) acc[a][b] = (floatx4)0.0f;

    const bf16* Abase = A + (size_t)blockIdx.x * 128 * K;
    const bf16* Bbase = BT + (size_t)blockIdx.y * 128 * K;

    for (int k0 = 0; k0 < K; k0 += 32) {
        __syncthreads();
#pragma unroll
        for (int i = 0; i < 2; ++i) {
            int c = wave * 128 + i * 64 + lane;
            int row = c >> 2, ko = (c & 3) * 8;
            async_copy16(As + c * 8, Abase + (size_t)row * K + k0 + ko);
            async_copy16(Bs + c * 8, Bbase + (size_t)row * K + k0 + ko);
        }
        __syncthreads();
        bf16x8 af[4], bfr[4];
#pragma unroll
        for (int mt = 0; mt < 4; ++mt)
            af[mt] = *(const bf16x8*)(As + (wm * 64 + mt * 16 + l16) * 32 + quad * 8);
#pragma unroll
        for (int nt = 0; nt < 4; ++nt)
            bfr[nt] = *(const bf16x8*)(Bs + (wn * 64 + nt * 16 + l16) * 32 + quad * 8);
#pragma unroll
        for (int mt = 0; mt < 4; ++mt)
#pragma unroll
            for (int nt = 0; nt < 4; ++nt)
                acc[mt][nt] = __builtin_amdgcn_mfma_f32_16x16x32_bf16(
                    af[mt], bfr[nt], acc[mt][nt], 0, 0, 0);
    }

    int crow0 = blockIdx.x * 128 + wm * 64;
    int ccol0 = blockIdx.y * 128 + wn * 64;
#pragma unroll
    for (int mt = 0; mt < 4; ++mt)
#pragma unroll
        for (int nt = 0; nt < 4; ++nt) {
            int col = ccol0 + nt * 16 + l16;
            float bs = bias[col];
#pragma unroll
            for (int r = 0; r < 4; ++r) {
                int row = crow0 + mt * 16 + quad * 4 + r;
                C[(size_t)row * NKV + col] = (bf16)(acc[mt][nt][r] + bs);
            }
        }
}

// ============================================================================
// K4: fused attention partial — one block per (batch, 32-token chunk):
// logits (q.K/32), chunk-local max + exp-sum, weighted-V partial accumulate.
// ============================================================================
__global__ __launch_bounds__(256) void attn_partial(
    const bf16* __restrict__ KV,
    const float* __restrict__ q,
    float* __restrict__ pacc,      // [B][NCH][EMBED]
    float* __restrict__ pms) {     // [B][NCH][2] = (m, s)
    __shared__ float qs[EMBED];
    __shared__ float lg[TCH];
    __shared__ float wt[TCH];
    int bid = blockIdx.x;
    int b = bid >> 7, ch = bid & (NCH - 1);
    int t0 = ch * TCH;
    int tid = threadIdx.x, w = tid >> 6, lane = tid & 63;
    *(float4*)(qs + tid * 4) = *(const float4*)(q + b * EMBED + tid * 4);
    __syncthreads();
    // logits: wave w computes t_local = w*8 .. w*8+7
    for (int j = 0; j < 8; ++j) {
        int tl = w * 8 + j;
        const bf16* Krow = KV + (size_t)(b * SS + t0 + tl) * NKV;
        float sum = 0.0f;
#pragma unroll
        for (int i = 0; i < 2; ++i) {
            int d0 = i * 512 + lane * 8;
            bf16x8 k8 = *(const bf16x8*)(Krow + d0);
            float4 qa = *(const float4*)(qs + d0);
            float4 qc = *(const float4*)(qs + d0 + 4);
            sum += qa.x * (float)k8[0] + qa.y * (float)k8[1] +
                   qa.z * (float)k8[2] + qa.w * (float)k8[3] +
                   qc.x * (float)k8[4] + qc.y * (float)k8[5] +
                   qc.z * (float)k8[6] + qc.w * (float)k8[7];
        }
#pragma unroll
        for (int o = 32; o; o >>= 1) sum += __shfl_down(sum, o);
        if (lane == 0) lg[tl] = sum * 0.03125f;     // 1/sqrt(1024)
    }
    __syncthreads();
    float m = -1e30f;
#pragma unroll
    for (int i = 0; i < TCH; ++i) m = fmaxf(m, lg[i]);
    if (tid < TCH) wt[tid] = expf(lg[tid] - m);
    __syncthreads();
    float ssum = 0.0f;
#pragma unroll
    for (int i = 0; i < TCH; ++i) ssum += wt[i];
    // AV partial: thread covers 4 d-cols
    int d4 = tid * 4;
    const bf16* Vb = KV + (size_t)(b * SS + t0) * NKV + EMBED + d4;
    float a0 = 0, a1 = 0, a2 = 0, a3 = 0;
#pragma unroll 4
    for (int t = 0; t < TCH; ++t) {
        bf16x4 v = *(const bf16x4*)(Vb + (size_t)t * NKV);
        float wv = wt[t];
        a0 += wv * (float)v.x; a1 += wv * (float)v.y;
        a2 += wv * (float)v.z; a3 += wv * (float)v.w;
    }
    float* pa = pacc + (size_t)(b * NCH + ch) * EMBED + d4;
    pa[0] = a0; pa[1] = a1; pa[2] = a2; pa[3] = a3;
    if (tid == 0) {
        pms[(b * NCH + ch) * 2 + 0] = m;
        pms[(b * NCH + ch) * 2 + 1] = ssum;
    }
}

// ============================================================================
// K5: combine partials -> h_final = h_last + softmax-weighted V sum.
// grid 32 = b(4) x dseg(8 of 128 d); 256 threads = 32 d-quads x 8 ts-groups.
// ============================================================================
__global__ void attn_combine(const float* __restrict__ pacc,
                             const float* __restrict__ pms,
                             const float* __restrict__ h_last,
                             float* __restrict__ h_final) {
    __shared__ float pmL[NCH], psL[NCH], eL[NCH];
    __shared__ float red[8][32][4];
    int b = blockIdx.x >> 3, g = blockIdx.x & 7;
    int tid = threadIdx.x;
    if (tid < NCH) {
        pmL[tid] = pms[(b * NCH + tid) * 2 + 0];
        psL[tid] = pms[(b * NCH + tid) * 2 + 1];
    }
    __syncthreads();
    float M = -1e30f;
#pragma unroll 8
    for (int i = 0; i < NCH; ++i) M = fmaxf(M, pmL[i]);
    if (tid < NCH) eL[tid] = expf(pmL[tid] - M);
    __syncthreads();
    float S = 0.0f;
#pragma unroll 8
    for (int i = 0; i < NCH; ++i) S += psL[i] * eL[i];
    int dq = tid & 31, tg = tid >> 5;
    int d4 = g * 128 + dq * 4;
    float a0 = 0, a1 = 0, a2 = 0, a3 = 0;
    for (int ts = tg * 16; ts < tg * 16 + 16; ++ts) {
        float e = eL[ts];
        const float* p = pacc + (size_t)(b * NCH + ts) * EMBED + d4;
        a0 += e * p[0]; a1 += e * p[1]; a2 += e * p[2]; a3 += e * p[3];
    }
    red[tg][dq][0] = a0; red[tg][dq][1] = a1;
    red[tg][dq][2] = a2; red[tg][dq][3] = a3;
    __syncthreads();
    if (tg == 0) {
#pragma unroll
        for (int i = 1; i < 8; ++i) {
            a0 += red[i][dq][0]; a1 += red[i][dq][1];
            a2 += red[i][dq][2]; a3 += red[i][dq][3];
        }
        float inv = 1.0f / S;
        const float* r = h_last + b * EMBED + d4;
        float* o = h_final + b * EMBED + d4;
        o[0] = r[0] + a0 * inv; o[1] = r[1] + a1 * inv;
        o[2] = r[2] + a2 * inv; o[3] = r[3] + a3 * inv;
    }
}

// ============================================================================
// K6: out partials. opart[seg][b][j] = sum_{d in seg} h_final[b][d]*out_w[d][j]
// grid (16 j-chunks of 2048, NSEG d-segs of 64); 8 cols/thread via 2 float4.
// ============================================================================
__global__ void out_gemm(const float* __restrict__ h_final,
                         const float* __restrict__ out_w,
                         float* __restrict__ opart) {
    __shared__ float hs[BB * 64];
    int tid = threadIdx.x;
    int seg = blockIdx.y, d0 = seg * 64;
    hs[tid] = h_final[(tid >> 6) * EMBED + d0 + (tid & 63)];
    __syncthreads();
    int j0 = blockIdx.x * 2048 + tid * 8;
    if (j0 >= VOCAB) return;
    floatx4 aL[BB], aH[BB];
#pragma unroll
    for (int b = 0; b < BB; ++b) { aL[b] = (floatx4)0.0f; aH[b] = (floatx4)0.0f; }
#pragma unroll 2
    for (int dd = 0; dd < 64; ++dd) {
        const float* wr = out_w + (size_t)(d0 + dd) * VOCAB + j0;
        float4 w0 = *(const float4*)wr;
        float4 w1 = *(const float4*)(wr + 4);
#pragma unroll
        for (int b = 0; b < BB; ++b) {
            float hv = hs[b * 64 + dd];
            aL[b][0] += hv * w0.x; aL[b][1] += hv * w0.y;
            aL[b][2] += hv * w0.z; aL[b][3] += hv * w0.w;
            aH[b][0] += hv * w1.x; aH[b][1] += hv * w1.y;
            aH[b][2] += hv * w1.z; aH[b][3] += hv * w1.w;
        }
    }
#pragma unroll
    for (int b = 0; b < BB; ++b) {
        float* op = opart + ((size_t)seg * BB + b) * VOCAB + j0;
        *(floatx4*)op = aL[b];
        *(floatx4*)(op + 4) = aH[b];
    }
}

// K6b: out[b][j] = out_b[j] + sum_seg opart[seg][b][j]
__global__ void out_reduce(const float* __restrict__ opart,
                           const float* __restrict__ out_b,
                           float* __restrict__ out) {
    int i = blockIdx.x * 256 + threadIdx.x;     // 128000
    if (i >= BB * VOCAB) return;
    int b = i / VOCAB, j = i - b * VOCAB;
    float s = out_b[j];
#pragma unroll
    for (int sg = 0; sg < NSEG; ++sg) s += opart[((size_t)sg * BB + b) * VOCAB + j];
    out[i] = s;
}

// ============================================================================
extern "C" void kernel_launch(void* const* d_in, const int* in_sizes, int n_in,
                              void* d_out, int out_size, void* d_ws, size_t ws_size,
                              hipStream_t stream) {
    const int*   x      = (const int*)d_in[0];
    const float* embed  = (const float*)d_in[1];
    const float* qkv_w  = (const float*)d_in[2];
    const float* qkv_b  = (const float*)d_in[3];
    const float* out_w  = (const float*)d_in[4];
    const float* out_b  = (const float*)d_in[5];
    float* out = (float*)d_out;

    char* ws = (char*)d_ws;
    // region [0, 32 MiB): h while gemm_kv runs; then attn partials; then opart.
    bf16*  h       = (bf16*)(ws);                         // 32 MiB (prep..gemm_kv)
    float* opart   = (float*)(ws);                        // 8.2 MiB (out_gemm..out_reduce)
    float* pacc    = (float*)(ws + 16777216);             // 2 MiB  (attn_partial..combine)
    float* pms     = (float*)(ws + 20971520);             // 4 KiB
    bf16*  KV      = (bf16*)(ws + 33554432);              // 64 MiB
    bf16*  WkvT    = (bf16*)(ws + 100663296);             // 4 MiB
    float* h_last  = (float*)(ws + 104857600);            // 16 KiB
    float* h_final = (float*)(ws + 104873984);            // 16 KiB
    float* q       = (float*)(ws + 104890368);            // 16 KiB

    prep<<<NTOK / 4 + 2048, 256, 0, stream>>>(x, embed, qkv_w, h, h_last, WkvT);
    q_fused<<<32, 256, 0, stream>>>(h_last, qkv_w, qkv_b, q);
    gemm_kv<<<dim3(NTOK / 128, NKV / 128), 256, 0, stream>>>(
        h, WkvT, qkv_b + EMBED, KV);
    attn_partial<<<BB * NCH, 256, 0, stream>>>(KV, q, pacc, pms);
    attn_combine<<<32, 256, 0, stream>>>(pacc, pms, h_last, h_final);
    out_gemm<<<dim3(16, NSEG), 256, 0, stream>>>(h_final, out_w, opart);
    out_reduce<<<(BB * VOCAB + 255) / 256, 256, 0, stream>>>(opart, out_b, out);
}

// Round 4
// 416.116 us; speedup vs baseline: 1.0049x; 1.0049x over previous
//
#include <hip/hip_runtime.h>
#include <hip/hip_bf16.h>

typedef __bf16 bf16;
typedef __bf16 bf16x4 __attribute__((ext_vector_type(4)));
typedef __bf16 bf16x8 __attribute__((ext_vector_type(8)));
typedef float floatx4 __attribute__((ext_vector_type(4)));

#define EMBED 1024
#define VOCAB 32000
#define BB    4
#define SS    4096
#define NTOK  (BB * SS)   // 16384
#define NKV   2048        // K and V concatenated
#define NSEG  32          // out_gemm d-segments
#define TCH   16          // attention t-chunk per block
#define NCH   (SS / TCH)  // 256 chunks per batch

// ---- async global->LDS, 16B per lane (lane-contiguous LDS dest required) ----
__device__ __forceinline__ void async_copy16(void* lds, const void* g) {
    __builtin_amdgcn_global_load_lds(
        (const __attribute__((address_space(1))) unsigned int*)g,
        (__attribute__((address_space(3))) unsigned int*)lds, 16, 0, 0);
}

// ============================================================================
// K1 "prep": bid < NTOK -> gather h[t] = bf16(embed[x[t]]), 1 token/block;
//            stash last token per batch (fp32) in h_last.
//            bid >= NTOK -> transpose+convert qkv_w[:,1024:3072] -> WkvT.
// ============================================================================
__global__ void prep(const int* __restrict__ x,
                     const float* __restrict__ embed,
                     const float* __restrict__ qkv_w,
                     bf16* __restrict__ h,
                     float* __restrict__ h_last,
                     bf16* __restrict__ WkvT) {
    __shared__ float T[32 * 33];
    int bid = blockIdx.x, tid = threadIdx.x;
    if (bid < NTOK) {
        int row = x[bid];
        float4 v = *(const float4*)(embed + (size_t)row * EMBED + tid * 4);
        bf16x4 o; o.x=(bf16)v.x; o.y=(bf16)v.y; o.z=(bf16)v.z; o.w=(bf16)v.w;
        *(bf16x4*)(h + (size_t)bid * EMBED + tid * 4) = o;
        if ((bid & (SS - 1)) == SS - 1)
            *(float4*)(h_last + (bid >> 12) * EMBED + tid * 4) = v;
    } else {
        int bw = bid - NTOK;                  // 0..2047
        int n0 = (bw & 63) * 32, d0 = (bw >> 6) * 32;
        int c = tid & 31, r = tid >> 5;
#pragma unroll
        for (int i = 0; i < 4; ++i) {
            int d = r + i * 8;
            T[c * 33 + d] = qkv_w[(size_t)(d0 + d) * (3 * EMBED) + EMBED + n0 + c];
        }
        __syncthreads();
#pragma unroll
        for (int i = 0; i < 4; ++i) {
            int n = r + i * 8;
            WkvT[(size_t)(n0 + n) * EMBED + d0 + c] = (bf16)T[n * 33 + c];
        }
    }
}

// ============================================================================
// K2: q[b] = h_last[b] @ qkv_w[:, 0:1024] + qkv_b[0:1024]  (32 blocks)
// ============================================================================
__global__ void q_fused(const float* __restrict__ h_last,
                        const float* __restrict__ qkv_w,
                        const float* __restrict__ qkv_b,
                        float* __restrict__ q) {
    __shared__ float hs[BB * EMBED];
    int tid = threadIdx.x;
    for (int i = tid; i < BB * EMBED / 4; i += 256)
        *(float4*)(hs + i * 4) = *(const float4*)(h_last + i * 4);
    __syncthreads();
    int w = tid >> 6, lane = tid & 63;
    int j = blockIdx.x * 32 + (lane & 31);
    int dh = lane >> 5;
    const float* hb = hs + w * EMBED + dh * 512;
    float acc = 0.0f;
#pragma unroll 8
    for (int d = 0; d < 512; ++d)
        acc += hb[d] * qkv_w[(size_t)(dh * 512 + d) * (3 * EMBED) + j];
    acc += __shfl_down(acc, 32);
    if (lane < 32) q[w * EMBED + j] = acc + qkv_b[j];
}

// ============================================================================
// K3: big GEMM, BK=64 + XOR-swizzled LDS K-slots (bank-conflict-free frags).
// KV[16384 x 2048] = h @ WkvT^T + bias.  LDS 32 KiB.
// slot kg' = kg ^ ((row>>1)&7): stager fetches swizzled source per lane
// (dest stays lane-contiguous as global_load_lds requires); readers XOR back.
// ============================================================================
#define SWZ(r) (((r) >> 1) & 7)
__global__ __launch_bounds__(256, 2) void gemm_kv(
    const bf16* __restrict__ A,    // 16384 x 1024 row-major
    const bf16* __restrict__ BT,   // 2048 x 1024
    const float* __restrict__ bias,// 2048
    bf16* __restrict__ C) {        // 16384 x 2048
    __shared__ bf16 As[128 * 64];
    __shared__ bf16 Bs[128 * 64];
    const int K = EMBED;
    int tid = threadIdx.x;
    int wave = tid >> 6, lane = tid & 63;
    int wm = wave >> 1, wn = wave & 1;
    int quad = lane >> 4, l16 = lane & 15;

    floatx4 acc[4][4];
#pragma unroll
    for (int a = 0; a < 4; ++a)
#pragma unroll
        for (int b = 0; b < 4; ++b) acc[a][b] = (floatx4)0.0f;

    const bf16* Abase = A + (size_t)blockIdx.x * 128 * K;
    const bf16* Bbase = BT + (size_t)blockIdx.y * 128 * K;

    for (int k0 = 0; k0 < K; k0 += 64) {
        __syncthreads();
#pragma unroll
        for (int j = 0; j < 4; ++j) {
            int c = wave * 256 + j * 64 + lane;     // 0..1023 slots of 16 B
            int row = c >> 3, kgp = c & 7;
            int kg = kgp ^ SWZ(row);                // which global K-slot lands here
            async_copy16(As + c * 8, Abase + (size_t)row * K + k0 + kg * 8);
            async_copy16(Bs + c * 8, Bbase + (size_t)row * K + k0 + kg * 8);
        }
        __syncthreads();
#pragma unroll
        for (int sub = 0; sub < 2; ++sub) {         // two 32-wide K chunks
            bf16x8 af[4], bfr[4];
#pragma unroll
            for (int mt = 0; mt < 4; ++mt) {
                int r = wm * 64 + mt * 16 + l16;
                int kg = sub * 4 + quad;
                af[mt] = *(const bf16x8*)(As + r * 64 + (kg ^ SWZ(r)) * 8);
            }
#pragma unroll
            for (int nt = 0; nt < 4; ++nt) {
                int r = wn * 64 + nt * 16 + l16;
                int kg = sub * 4 + quad;
                bfr[nt] = *(const bf16x8*)(Bs + r * 64 + (kg ^ SWZ(r)) * 8);
            }
#pragma unroll
            for (int mt = 0; mt < 4; ++mt)
#pragma unroll
                for (int nt = 0; nt < 4; ++nt)
                    acc[mt][nt] = __builtin_amdgcn_mfma_f32_16x16x32_bf16(
                        af[mt], bfr[nt], acc[mt][nt], 0, 0, 0);
        }
    }

    int crow0 = blockIdx.x * 128 + wm * 64;
    int ccol0 = blockIdx.y * 128 + wn * 64;
#pragma unroll
    for (int mt = 0; mt < 4; ++mt)
#pragma unroll
        for (int nt = 0; nt < 4; ++nt) {
            int col = ccol0 + nt * 16 + l16;
            float bs = bias[col];
#pragma unroll
            for (int r = 0; r < 4; ++r) {
                int row = crow0 + mt * 16 + quad * 4 + r;
                C[(size_t)row * NKV + col] = (bf16)(acc[mt][nt][r] + bs);
            }
        }
}

// ============================================================================
// K4: attention partials — block = (batch, 16-token chunk), 128 threads.
// logits via 2 waves x 8 t; V accumulate via bf16x8 (16 B/lane).
// ============================================================================
__global__ __launch_bounds__(128) void attn_partial(
    const bf16* __restrict__ KV,
    const float* __restrict__ q,
    float* __restrict__ pacc,      // [B][NCH][EMBED]
    float* __restrict__ pms) {     // [B][NCH][2] = (m, s)
    __shared__ float qs[EMBED];
    __shared__ float lg[TCH], wt[TCH];
    int bid = blockIdx.x;                       // BB*NCH = 1024
    int b = bid >> 8, ch = bid & (NCH - 1);
    int t0 = ch * TCH;
    int tid = threadIdx.x, w = tid >> 6, lane = tid & 63;
    *(float4*)(qs + tid * 8)     = *(const float4*)(q + b * EMBED + tid * 8);
    *(float4*)(qs + tid * 8 + 4) = *(const float4*)(q + b * EMBED + tid * 8 + 4);
    __syncthreads();
    for (int j = 0; j < 8; ++j) {
        int tl = w * 8 + j;
        const bf16* Krow = KV + (size_t)(b * SS + t0 + tl) * NKV;
        float sum = 0.0f;
#pragma unroll
        for (int i = 0; i < 2; ++i) {
            int d0 = i * 512 + lane * 8;
            bf16x8 k8 = *(const bf16x8*)(Krow + d0);
            float4 qa = *(const float4*)(qs + d0);
            float4 qc = *(const float4*)(qs + d0 + 4);
            sum += qa.x * (float)k8[0] + qa.y * (float)k8[1] +
                   qa.z * (float)k8[2] + qa.w * (float)k8[3] +
                   qc.x * (float)k8[4] + qc.y * (float)k8[5] +
                   qc.z * (float)k8[6] + qc.w * (float)k8[7];
        }
#pragma unroll
        for (int o = 32; o; o >>= 1) sum += __shfl_down(sum, o);
        if (lane == 0) lg[tl] = sum * 0.03125f;
    }
    __syncthreads();
    float m = -1e30f;
#pragma unroll
    for (int i = 0; i < TCH; ++i) m = fmaxf(m, lg[i]);
    if (tid < TCH) wt[tid] = expf(lg[tid] - m);
    __syncthreads();
    float ssum = 0.0f;
#pragma unroll
    for (int i = 0; i < TCH; ++i) ssum += wt[i];
    int d8 = tid * 8;
    const bf16* Vb = KV + (size_t)(b * SS + t0) * NKV + EMBED + d8;
    float a[8];
#pragma unroll
    for (int k = 0; k < 8; ++k) a[k] = 0.0f;
#pragma unroll 4
    for (int t = 0; t < TCH; ++t) {
        bf16x8 v = *(const bf16x8*)(Vb + (size_t)t * NKV);
        float wv = wt[t];
#pragma unroll
        for (int k = 0; k < 8; ++k) a[k] += wv * (float)v[k];
    }
    float* pa = pacc + (size_t)(b * NCH + ch) * EMBED + d8;
    *(floatx4*)pa = *(floatx4*)&a[0];
    *(floatx4*)(pa + 4) = *(floatx4*)&a[4];
    if (tid == 0) {
        pms[(b * NCH + ch) * 2 + 0] = m;
        pms[(b * NCH + ch) * 2 + 1] = ssum;
    }
}

// ============================================================================
// K5: combine partials -> h_final = h_last + softmax-weighted V sum.
// grid 32 = b(4) x dseg(8 of 128 d); 256 threads = 32 d-quads x 8 ts-groups.
// ============================================================================
__global__ void attn_combine(const float* __restrict__ pacc,
                             const float* __restrict__ pms,
                             const float* __restrict__ h_last,
                             float* __restrict__ h_final) {
    __shared__ float pmL[NCH], psL[NCH], eL[NCH];
    __shared__ float red[8][32][4];
    int b = blockIdx.x >> 3, g = blockIdx.x & 7;
    int tid = threadIdx.x;
    pmL[tid] = pms[(b * NCH + tid) * 2 + 0];
    psL[tid] = pms[(b * NCH + tid) * 2 + 1];
    __syncthreads();
    float M = -1e30f;
#pragma unroll 8
    for (int i = 0; i < NCH; ++i) M = fmaxf(M, pmL[i]);
    eL[tid] = expf(pmL[tid] - M);
    __syncthreads();
    float S = 0.0f;
#pragma unroll 8
    for (int i = 0; i < NCH; ++i) S += psL[i] * eL[i];
    int dq = tid & 31, tg = tid >> 5;
    int d4 = g * 128 + dq * 4;
    float a0 = 0, a1 = 0, a2 = 0, a3 = 0;
    for (int ts = tg * 32; ts < tg * 32 + 32; ++ts) {
        float e = eL[ts];
        const float* p = pacc + (size_t)(b * NCH + ts) * EMBED + d4;
        a0 += e * p[0]; a1 += e * p[1]; a2 += e * p[2]; a3 += e * p[3];
    }
    red[tg][dq][0] = a0; red[tg][dq][1] = a1;
    red[tg][dq][2] = a2; red[tg][dq][3] = a3;
    __syncthreads();
    if (tg == 0) {
#pragma unroll
        for (int i = 1; i < 8; ++i) {
            a0 += red[i][dq][0]; a1 += red[i][dq][1];
            a2 += red[i][dq][2]; a3 += red[i][dq][3];
        }
        float inv = 1.0f / S;
        const float* r = h_last + b * EMBED + d4;
        float* o = h_final + b * EMBED + d4;
        o[0] = r[0] + a0 * inv; o[1] = r[1] + a1 * inv;
        o[2] = r[2] + a2 * inv; o[3] = r[3] + a3 * inv;
    }
}

// ============================================================================
// K6: out partials. grid (16 j-chunks of 2048, NSEG=32 d-segs of 32 rows);
// 8 cols/thread via 2 float4 — 512 blocks for 2x loads in flight.
// ============================================================================
__global__ void out_gemm(const float* __restrict__ h_final,
                         const float* __restrict__ out_w,
                         float* __restrict__ opart) {
    __shared__ float hs[BB * 32];
    int tid = threadIdx.x;
    int seg = blockIdx.y, d0 = seg * 32;
    if (tid < BB * 32) hs[tid] = h_final[(tid >> 5) * EMBED + d0 + (tid & 31)];
    __syncthreads();
    int j0 = blockIdx.x * 2048 + tid * 8;
    if (j0 >= VOCAB) return;
    floatx4 aL[BB], aH[BB];
#pragma unroll
    for (int b = 0; b < BB; ++b) { aL[b] = (floatx4)0.0f; aH[b] = (floatx4)0.0f; }
#pragma unroll 2
    for (int dd = 0; dd < 32; ++dd) {
        const float* wr = out_w + (size_t)(d0 + dd) * VOCAB + j0;
        float4 w0 = *(const float4*)wr;
        float4 w1 = *(const float4*)(wr + 4);
#pragma unroll
        for (int b = 0; b < BB; ++b) {
            float hv = hs[b * 32 + dd];
            aL[b][0] += hv * w0.x; aL[b][1] += hv * w0.y;
            aL[b][2] += hv * w0.z; aL[b][3] += hv * w0.w;
            aH[b][0] += hv * w1.x; aH[b][1] += hv * w1.y;
            aH[b][2] += hv * w1.z; aH[b][3] += hv * w1.w;
        }
    }
#pragma unroll
    for (int b = 0; b < BB; ++b) {
        float* op = opart + ((size_t)seg * BB + b) * VOCAB + j0;
        *(floatx4*)op = aL[b];
        *(floatx4*)(op + 4) = aH[b];
    }
}

// K6b: out[b][j] = out_b[j] + sum_seg opart[seg][b][j]  (float4)
__global__ void out_reduce(const float* __restrict__ opart,
                           const float* __restrict__ out_b,
                           float* __restrict__ out) {
    int i4 = (blockIdx.x * 256 + threadIdx.x) * 4;  // 128000 elems, 125 blocks
    if (i4 >= BB * VOCAB) return;
    int b = i4 / VOCAB, j = i4 - b * VOCAB;
    floatx4 s = *(const floatx4*)(out_b + j);
#pragma unroll 4
    for (int sg = 0; sg < NSEG; ++sg)
        s += *(const floatx4*)(opart + ((size_t)sg * BB + b) * VOCAB + j);
    *(floatx4*)(out + i4) = s;
}

// ============================================================================
extern "C" void kernel_launch(void* const* d_in, const int* in_sizes, int n_in,
                              void* d_out, int out_size, void* d_ws, size_t ws_size,
                              hipStream_t stream) {
    const int*   x      = (const int*)d_in[0];
    const float* embed  = (const float*)d_in[1];
    const float* qkv_w  = (const float*)d_in[2];
    const float* qkv_b  = (const float*)d_in[3];
    const float* out_w  = (const float*)d_in[4];
    const float* out_b  = (const float*)d_in[5];
    float* out = (float*)d_out;

    char* ws = (char*)d_ws;
    // region [0, 32 MiB): h (prep..gemm_kv); then opart (out_gemm..out_reduce)
    bf16*  h       = (bf16*)(ws);                         // 32 MiB
    float* opart   = (float*)(ws);                        // 16.4 MiB
    float* pacc    = (float*)(ws + 16777216);             // 4 MiB wait-- overlaps opart!
    bf16*  KV      = (bf16*)(ws + 33554432);              // 64 MiB
    bf16*  WkvT    = (bf16*)(ws + 100663296);             // 4 MiB
    float* h_last  = (float*)(ws + 104857600);            // 16 KiB
    float* h_final = (float*)(ws + 104873984);            // 16 KiB
    float* q       = (float*)(ws + 104890368);            // 16 KiB
    float* pms     = (float*)(ws + 104906752);            // 8 KiB
    // NOTE: opart (16.4 MiB at ws+0) would overlap pacc (ws+16 MiB).
    // pacc is consumed by attn_combine BEFORE out_gemm writes opart, but the
    // regions must still be disjoint for safety against reordering: place
    // pacc after WkvT instead.
    pacc = (float*)(ws + 104914944);                      // 4 MiB

    prep<<<NTOK + 2048, 256, 0, stream>>>(x, embed, qkv_w, h, h_last, WkvT);
    q_fused<<<32, 256, 0, stream>>>(h_last, qkv_w, qkv_b, q);
    gemm_kv<<<dim3(NTOK / 128, NKV / 128), 256, 0, stream>>>(
        h, WkvT, qkv_b + EMBED, KV);
    attn_partial<<<BB * NCH, 128, 0, stream>>>(KV, q, pacc, pms);
    attn_combine<<<32, 256, 0, stream>>>(pacc, pms, h_last, h_final);
    out_gemm<<<dim3(16, NSEG), 256, 0, stream>>>(h_final, out_w, opart);
    out_reduce<<<125, 256, 0, stream>>>(opart, out_b, out);
}